// Round 2
// baseline (540.253 us; speedup 1.0000x reference)
//
#include <hip/hip_runtime.h>
#include <math.h>

#define BB 16
#define LC 1024
#define LQ 1024
#define DD 256
#define CT 16
#define QT 32

// ws layout (floats):
// [0, 16384)        qterm[b][q]
// [16384, 32768)    cterm[b][c]
// [32768, 49152)    rowmax[b][c]  (= cterm + max_q(qterm + m-dot))
// [49152, 53248)    q2cvec[b][d]

__global__ __launch_bounds__(256) void k_terms(const float* __restrict__ ctx,
                                               const float* __restrict__ qst,
                                               const float* __restrict__ w,
                                               float* __restrict__ ws) {
    int gw = (blockIdx.x * 256 + threadIdx.x) >> 6;   // global wave id, 0..32767
    int lane = threadIdx.x & 63;
    bool isQ = gw >= BB * LC;
    int row = isQ ? gw - BB * LC : gw;                // b*1024 + l
    const float* src = isQ ? qst : ctx;
    const float* wp  = isQ ? (w + DD) : w;            // wq : wc
    float4 x  = *(const float4*)(src + (size_t)row * DD + lane * 4);
    float4 wv = *(const float4*)(wp + lane * 4);
    float d = x.x * wv.x + x.y * wv.y + x.z * wv.z + x.w * wv.w;
    #pragma unroll
    for (int off = 32; off; off >>= 1) d += __shfl_xor(d, off);
    float* dst = ws + (isQ ? 0 : BB * LQ);            // qterm at 0, cterm at 16384
    if (lane == 0) dst[row] = d;
}

__global__ __launch_bounds__(256) void k_main(const float* __restrict__ ctx,
                                              const float* __restrict__ qst,
                                              const float* __restrict__ w,
                                              const float* __restrict__ ws,
                                              float* __restrict__ out,
                                              float* __restrict__ rowmax_out) {
    __shared__ float cm[CT][DD + 4];     // context * wm, padded (2-way max conflict)
    __shared__ float Qs[QT][DD + 4];
    __shared__ float sS[CT][QT + 1];     // stride 33 -> conflict-free scalar reads
    __shared__ float qtS[QT];

    int t = threadIdx.x;
    int b = blockIdx.y;
    int c0 = blockIdx.x * CT;
    const float* qterm = ws;
    const float* cterm = ws + BB * LQ;

    // stage cm = context*wm : 16x256 floats = 1024 float4, 4 per thread
    {
        const float* wm = w + 2 * DD;
        #pragma unroll
        for (int k = 0; k < 4; ++k) {
            int f = t + k * 256;
            int row = f >> 6;
            int c4 = (f & 63) * 4;
            float4 x  = *(const float4*)(ctx + (size_t)(b * LC + c0 + row) * DD + c4);
            float4 wv = *(const float4*)(wm + c4);
            x.x *= wv.x; x.y *= wv.y; x.z *= wv.z; x.w *= wv.w;
            *(float4*)&cm[row][c4] = x;
        }
    }

    int r   = t & 15;        // c-row within tile
    int cg  = t >> 4;        // 0..15
    int col0 = cg * 16;      // 16-col slice of D owned by this thread
    float acc[16];
    #pragma unroll
    for (int j = 0; j < 16; ++j) acc[j] = 0.f;
    float m = -1e30f, l = 0.f;

    for (int qt = 0; qt < LQ / QT; ++qt) {
        __syncthreads();     // protect Qs/sS from previous iteration's readers
        // stage Qs: 32x256 floats = 2048 float4, 8 per thread
        #pragma unroll
        for (int k = 0; k < 8; ++k) {
            int f = t + k * 256;
            int row = f >> 6;
            int c4 = (f & 63) * 4;
            *(float4*)&Qs[row][c4] =
                *(const float4*)(qst + (size_t)(b * LQ + qt * QT + row) * DD + c4);
        }
        if (t < QT) qtS[t] = qterm[b * LQ + qt * QT + t];
        __syncthreads();

        // s-compute: this thread does rows r, q in {2*cg, 2*cg+1}
        {
            int q0 = cg * 2;
            float s0 = 0.f, s1 = 0.f;
            #pragma unroll 8
            for (int d4 = 0; d4 < DD / 4; ++d4) {
                float4 a  = *(const float4*)&cm[r][d4 * 4];
                float4 b0 = *(const float4*)&Qs[q0][d4 * 4];
                float4 b1 = *(const float4*)&Qs[q0 + 1][d4 * 4];
                s0 += a.x * b0.x + a.y * b0.y + a.z * b0.z + a.w * b0.w;
                s1 += a.x * b1.x + a.y * b1.y + a.z * b1.z + a.w * b1.w;
            }
            sS[r][q0]     = s0 + qtS[q0];
            sS[r][q0 + 1] = s1 + qtS[q0 + 1];
        }
        __syncthreads();

        // online softmax + PV (each thread: its row r, its 16-col slice)
        float rmax = -1e30f;
        #pragma unroll
        for (int q = 0; q < QT; ++q) rmax = fmaxf(rmax, sS[r][q]);
        float mn = fmaxf(m, rmax);
        float scale = __expf(m - mn);
        l *= scale;
        #pragma unroll
        for (int j = 0; j < 16; ++j) acc[j] *= scale;
        for (int q = 0; q < QT; ++q) {
            float p = __expf(sS[r][q] - mn);
            l += p;
            #pragma unroll
            for (int j4 = 0; j4 < 4; ++j4) {
                float4 qv = *(const float4*)&Qs[q][col0 + j4 * 4];
                acc[j4 * 4 + 0] += p * qv.x;
                acc[j4 * 4 + 1] += p * qv.y;
                acc[j4 * 4 + 2] += p * qv.z;
                acc[j4 * 4 + 3] += p * qv.w;
            }
        }
        m = mn;
    }

    float inv = 1.0f / l;
    int orow = b * LC + c0 + r;
    #pragma unroll
    for (int j4 = 0; j4 < 4; ++j4) {
        float4 v;
        v.x = acc[j4 * 4 + 0] * inv;
        v.y = acc[j4 * 4 + 1] * inv;
        v.z = acc[j4 * 4 + 2] * inv;
        v.w = acc[j4 * 4 + 3] * inv;
        *(float4*)(out + (size_t)orow * DD + col0 + j4 * 4) = v;
    }
    if (cg == 0) rowmax_out[orow] = m + cterm[orow];
}

__global__ __launch_bounds__(256) void k_q2c(const float* __restrict__ ctx,
                                             const float* __restrict__ rowmax,
                                             float* __restrict__ q2cvec) {
    __shared__ float sm[LC];
    __shared__ float red[256];
    int b = blockIdx.x;
    int chunk = blockIdx.y;    // 0..31, 32 c's each
    int t = threadIdx.x;
    const float* rm = rowmax + b * LC;

    float lmax = -1e30f;
    #pragma unroll
    for (int k = 0; k < 4; ++k) {
        float v = rm[t + k * 256];
        sm[t + k * 256] = v;
        lmax = fmaxf(lmax, v);
    }
    red[t] = lmax;
    __syncthreads();
    for (int s = 128; s > 0; s >>= 1) {
        if (t < s) red[t] = fmaxf(red[t], red[t + s]);
        __syncthreads();
    }
    float gmax = red[0];
    __syncthreads();
    float lsum = 0.f;
    #pragma unroll
    for (int k = 0; k < 4; ++k) {
        int i = t + k * 256;
        float e = __expf(sm[i] - gmax);
        sm[i] = e;
        lsum += e;
    }
    red[t] = lsum;
    __syncthreads();
    for (int s = 128; s > 0; s >>= 1) {
        if (t < s) red[t] += red[t + s];
        __syncthreads();
    }
    float inv = 1.0f / red[0];

    int c0 = chunk * 32;
    float acc = 0.f;
    for (int c = c0; c < c0 + 32; ++c)
        acc += sm[c] * ctx[(size_t)(b * LC + c) * DD + t];
    atomicAdd(&q2cvec[b * DD + t], acc * inv);
}

__global__ __launch_bounds__(256) void k_bcast(const float* __restrict__ q2cvec,
                                               float* __restrict__ out2) {
    int g = blockIdx.x * 256 + threadIdx.x;   // float4 id, 0..1048575
    int b  = g >> 16;                          // 1024*64 float4 per batch
    int d4 = g & 63;
    ((float4*)out2)[g] = ((const float4*)q2cvec)[b * 64 + d4];
}

extern "C" void kernel_launch(void* const* d_in, const int* in_sizes, int n_in,
                              void* d_out, int out_size, void* d_ws, size_t ws_size,
                              hipStream_t stream) {
    const float* ctx = (const float*)d_in[0];
    const float* qst = (const float*)d_in[1];
    const float* w   = (const float*)d_in[2];
    float* out = (float*)d_out;
    float* ws  = (float*)d_ws;

    float* rowmax = ws + 32768;
    float* q2cvec = ws + 49152;

    hipMemsetAsync(q2cvec, 0, BB * DD * sizeof(float), stream);

    // cterm/qterm: 2*16*1024 rows, 1 wave each, 4 waves/block
    k_terms<<<(2 * BB * LC) / 4, 256, 0, stream>>>(ctx, qst, w, ws);

    k_main<<<dim3(LC / CT, BB), 256, 0, stream>>>(ctx, qst, w, ws, out, rowmax);

    k_q2c<<<dim3(BB, 32), 256, 0, stream>>>(ctx, rowmax, q2cvec);

    k_bcast<<<(BB * LC * DD / 4) / 256, 256, 0, stream>>>(q2cvec, out + (size_t)BB * LC * DD);
}

// Round 4
// 184.113 us; speedup vs baseline: 2.9344x; 2.9344x over previous
//
#include <hip/hip_runtime.h>
#include <math.h>

#define BB 16
#define LC 1024
#define LQ 1024
#define DD 256

#define CTB 64     // c rows per block
#define QTB 64     // q rows per tile
#define CM_S 264   // LDS stride (elems) for CMs/Qs: 528 B = 33*16, conflict-free
#define QT_S 72    // LDS stride (elems) for Qt/sP: 144 B = 9*16, conflict-free

typedef __attribute__((ext_vector_type(4))) float f32x4;
typedef __attribute__((ext_vector_type(8))) short bf16x8;
typedef __attribute__((ext_vector_type(4))) short bf16x4;

__device__ inline short f2bf(float f) {
    union { float f; unsigned u; } v; v.f = f;
    unsigned r = v.u + 0x7FFFu + ((v.u >> 16) & 1u);   // RNE
    return (short)(r >> 16);
}

// ws layout (floats):
// [0, 16384)        qterm[b][q]
// [16384, 32768)    cterm[b][c]
// [32768, 49152)    rowmax[b][c]
// [49152, 53248)    q2cvec[b][d]

__global__ __launch_bounds__(256) void k_terms(const float* __restrict__ ctx,
                                               const float* __restrict__ qst,
                                               const float* __restrict__ w,
                                               float* __restrict__ ws) {
    int gw = (blockIdx.x * 256 + threadIdx.x) >> 6;
    int lane = threadIdx.x & 63;
    bool isQ = gw >= BB * LC;
    int row = isQ ? gw - BB * LC : gw;
    const float* src = isQ ? qst : ctx;
    const float* wp  = isQ ? (w + DD) : w;
    float4 x  = *(const float4*)(src + (size_t)row * DD + lane * 4);
    float4 wv = *(const float4*)(wp + lane * 4);
    float d = x.x * wv.x + x.y * wv.y + x.z * wv.z + x.w * wv.w;
    #pragma unroll
    for (int off = 32; off; off >>= 1) d += __shfl_xor(d, off);
    float* dst = ws + (isQ ? 0 : BB * LQ);
    if (lane == 0) dst[row] = d;
}

__global__ __launch_bounds__(256, 1) void k_main(const float* __restrict__ ctx,
                                                 const float* __restrict__ qst,
                                                 const float* __restrict__ wght,
                                                 const float* __restrict__ ws,
                                                 float* __restrict__ out,
                                                 float* __restrict__ rowmax_out) {
    __shared__ short CMs[CTB][CM_S];   // ctx*wm, bf16, row-major (c, d)
    __shared__ short Qs [QTB][CM_S];   // Q tile, bf16, row-major (q, d)
    __shared__ short Qt [DD][QT_S];    // Q tile transposed (d, q)
    __shared__ short sP [CTB][QT_S];   // P tile bf16 (c, q)
    __shared__ float qtS[QTB];
    __shared__ float scaleS[CTB];
    __shared__ float sLinv[CTB];

    const int t  = threadIdx.x;
    const int l  = t & 63;
    const int wv = t >> 6;       // wave 0..3
    const int lx = l & 15;
    const int ls = l >> 4;       // 0..3
    const int b  = blockIdx.y;
    const int c0 = blockIdx.x * CTB;

    const float* qterm = ws;
    const float* cterm = ws + BB * LQ;

    // ---- stage CM = ctx * wm (once): wave wv stages local c rows [16wv,16wv+16)
    #pragma unroll
    for (int kq = 0; kq < 4; ++kq) {
        #pragma unroll
        for (int jd = 0; jd < 4; ++jd) {
            int cl = 16 * wv + 4 * kq + ls;
            int d0 = 64 * jd + 4 * lx;
            const float4 x  = *(const float4*)(ctx + ((size_t)(b * LC + c0 + cl)) * DD + d0);
            const float4 wm = *(const float4*)(wght + 2 * DD + d0);
            bf16x4 o;
            o[0] = f2bf(x.x * wm.x); o[1] = f2bf(x.y * wm.y);
            o[2] = f2bf(x.z * wm.z); o[3] = f2bf(x.w * wm.w);
            *(bf16x4*)&CMs[cl][d0] = o;
        }
    }

    float mrun[4], lrun[4];
    f32x4 oacc[4][4];
    #pragma unroll
    for (int r = 0; r < 4; ++r) { mrun[r] = -1e30f; lrun[r] = 0.f; }
    #pragma unroll
    for (int cf = 0; cf < 4; ++cf)
        #pragma unroll
        for (int df = 0; df < 4; ++df)
            oacc[cf][df] = (f32x4){0.f, 0.f, 0.f, 0.f};

    for (int qt = 0; qt < LQ / QTB; ++qt) {
        __syncthreads();   // prev PV done -> safe to overwrite Qs/Qt

        // ---- stage Qs (row-major) + Qt (transposed via 4x4 shfl butterfly)
        #pragma unroll
        for (int kq = 0; kq < 4; ++kq) {
            #pragma unroll
            for (int jd = 0; jd < 4; ++jd) {
                int ql = 16 * wv + 4 * kq + ls;
                int d0 = 64 * jd + 4 * lx;
                float4 x = *(const float4*)(qst + ((size_t)(b * LQ + qt * QTB + ql)) * DD + d0);
                bf16x4 o;
                o[0] = f2bf(x.x); o[1] = f2bf(x.y); o[2] = f2bf(x.z); o[3] = f2bf(x.w);
                *(bf16x4*)&Qs[ql][d0] = o;
                // 4x4 transpose among lanes {lx, lx+16, lx+32, lx+48}
                float X[4] = {x.x, x.y, x.z, x.w};
                float P1[4], X1[4], P2[4], X2[4];
                #pragma unroll
                for (int e = 0; e < 4; ++e) P1[e] = __shfl_xor(X[e ^ 1], 16);
                #pragma unroll
                for (int e = 0; e < 4; ++e) X1[e] = ((ls & 1) == (e & 1)) ? X[e] : P1[e];
                #pragma unroll
                for (int e = 0; e < 4; ++e) P2[e] = __shfl_xor(X1[e ^ 2], 32);
                #pragma unroll
                for (int e = 0; e < 4; ++e) X2[e] = ((ls & 2) == (e & 2)) ? X1[e] : P2[e];
                int dl = 64 * jd + 4 * lx + ls;      // lane now owns column dl, rows 16wv+4kq..+3
                bf16x4 ot;
                ot[0] = f2bf(X2[0]); ot[1] = f2bf(X2[1]); ot[2] = f2bf(X2[2]); ot[3] = f2bf(X2[3]);
                *(bf16x4*)&Qt[dl][16 * wv + 4 * kq] = ot;
            }
        }
        if (t < QTB) qtS[t] = qterm[b * LQ + qt * QTB + t];
        __syncthreads();

        // ---- S = CM @ Q^T  (wave wv: c rows 16wv..+16, all 64 q)
        f32x4 sacc[4];
        #pragma unroll
        for (int f = 0; f < 4; ++f) sacc[f] = (f32x4){0.f, 0.f, 0.f, 0.f};
        #pragma unroll
        for (int kk = 0; kk < 8; ++kk) {
            bf16x8 a = *(const bf16x8*)&CMs[16 * wv + lx][32 * kk + 8 * ls];
            #pragma unroll
            for (int f = 0; f < 4; ++f) {
                bf16x8 bq = *(const bf16x8*)&Qs[16 * f + lx][32 * kk + 8 * ls];
                sacc[f] = __builtin_amdgcn_mfma_f32_16x16x32_bf16(a, bq, sacc[f], 0, 0, 0);
            }
        }
        // D-layout: col q = 16f + lx ; row c = 16wv + 4*ls + r

        // ---- qterm + online softmax (per c row)
        #pragma unroll
        for (int f = 0; f < 4; ++f) {
            float qv = qtS[16 * f + lx];
            #pragma unroll
            for (int r = 0; r < 4; ++r) sacc[f][r] += qv;
        }
        float scl[4];
        #pragma unroll
        for (int r = 0; r < 4; ++r) {
            float v = fmaxf(fmaxf(sacc[0][r], sacc[1][r]), fmaxf(sacc[2][r], sacc[3][r]));
            v = fmaxf(v, __shfl_xor(v, 1));
            v = fmaxf(v, __shfl_xor(v, 2));
            v = fmaxf(v, __shfl_xor(v, 4));
            v = fmaxf(v, __shfl_xor(v, 8));
            float mn = fmaxf(mrun[r], v);
            scl[r] = __expf(mrun[r] - mn);
            mrun[r] = mn;
            lrun[r] *= scl[r];
        }
        float p[4][4];
        float rs[4] = {0.f, 0.f, 0.f, 0.f};
        #pragma unroll
        for (int f = 0; f < 4; ++f)
            #pragma unroll
            for (int r = 0; r < 4; ++r) {
                p[f][r] = __expf(sacc[f][r] - mrun[r]);
                rs[r] += p[f][r];
            }
        #pragma unroll
        for (int r = 0; r < 4; ++r) {
            float v = rs[r];
            v += __shfl_xor(v, 1);
            v += __shfl_xor(v, 2);
            v += __shfl_xor(v, 4);
            v += __shfl_xor(v, 8);
            lrun[r] += v;
        }
        #pragma unroll
        for (int f = 0; f < 4; ++f)
            #pragma unroll
            for (int r = 0; r < 4; ++r)
                sP[16 * wv + 4 * ls + r][16 * f + lx] = f2bf(p[f][r]);
        if (lx == 0) {
            #pragma unroll
            for (int r = 0; r < 4; ++r) scaleS[16 * wv + 4 * ls + r] = scl[r];
        }
        __syncthreads();

        // ---- PV: wave wv owns d slice [64wv, 64wv+64), all 64 c rows
        #pragma unroll
        for (int cf = 0; cf < 4; ++cf) {
            #pragma unroll
            for (int r = 0; r < 4; ++r) {
                float s = scaleS[16 * cf + 4 * ls + r];
                #pragma unroll
                for (int df = 0; df < 4; ++df) oacc[cf][df][r] *= s;
            }
        }
        #pragma unroll
        for (int kk = 0; kk < 2; ++kk) {
            bf16x8 pa[4];
            #pragma unroll
            for (int cf = 0; cf < 4; ++cf)
                pa[cf] = *(const bf16x8*)&sP[16 * cf + lx][32 * kk + 8 * ls];
            #pragma unroll
            for (int df = 0; df < 4; ++df) {
                bf16x8 qb = *(const bf16x8*)&Qt[64 * wv + 16 * df + lx][32 * kk + 8 * ls];
                #pragma unroll
                for (int cf = 0; cf < 4; ++cf)
                    oacc[cf][df] = __builtin_amdgcn_mfma_f32_16x16x32_bf16(pa[cf], qb, oacc[cf][df], 0, 0, 0);
            }
        }
    }

    // ---- epilogue
    if (lx == 0) {
        #pragma unroll
        for (int r = 0; r < 4; ++r) {
            int cl = 16 * wv + 4 * ls + r;
            sLinv[cl] = 1.0f / lrun[r];
            int c = b * LC + c0 + cl;
            rowmax_out[c] = mrun[r] + cterm[c];
        }
    }
    __syncthreads();
    #pragma unroll
    for (int cf = 0; cf < 4; ++cf) {
        #pragma unroll
        for (int r = 0; r < 4; ++r) {
            float li = sLinv[16 * cf + 4 * ls + r];
            size_t row = (size_t)(b * LC + c0 + 16 * cf + 4 * ls + r) * DD;
            #pragma unroll
            for (int df = 0; df < 4; ++df)
                out[row + 64 * wv + 16 * df + lx] = oacc[cf][df][r] * li;
        }
    }
}

__global__ __launch_bounds__(256) void k_q2c(const float* __restrict__ ctx,
                                             const float* __restrict__ rowmax,
                                             float* __restrict__ q2cvec) {
    __shared__ float sm[LC];
    __shared__ float red[256];
    int b = blockIdx.x;
    int chunk = blockIdx.y;
    int t = threadIdx.x;
    const float* rm = rowmax + b * LC;

    float lmax = -1e30f;
    #pragma unroll
    for (int k = 0; k < 4; ++k) {
        float v = rm[t + k * 256];
        sm[t + k * 256] = v;
        lmax = fmaxf(lmax, v);
    }
    red[t] = lmax;
    __syncthreads();
    for (int s = 128; s > 0; s >>= 1) {
        if (t < s) red[t] = fmaxf(red[t], red[t + s]);
        __syncthreads();
    }
    float gmax = red[0];
    __syncthreads();
    float lsum = 0.f;
    #pragma unroll
    for (int k = 0; k < 4; ++k) {
        int i = t + k * 256;
        float e = __expf(sm[i] - gmax);
        sm[i] = e;
        lsum += e;
    }
    red[t] = lsum;
    __syncthreads();
    for (int s = 128; s > 0; s >>= 1) {
        if (t < s) red[t] += red[t + s];
        __syncthreads();
    }
    float inv = 1.0f / red[0];

    int c0 = chunk * 32;
    float acc = 0.f;
    for (int c = c0; c < c0 + 32; ++c)
        acc += sm[c] * ctx[(size_t)(b * LC + c) * DD + t];
    atomicAdd(&q2cvec[b * DD + t], acc * inv);
}

__global__ __launch_bounds__(256) void k_bcast(const float* __restrict__ q2cvec,
                                               float* __restrict__ out2) {
    int g = blockIdx.x * 256 + threadIdx.x;
    int b  = g >> 16;
    int d4 = g & 63;
    ((float4*)out2)[g] = ((const float4*)q2cvec)[b * 64 + d4];
}

extern "C" void kernel_launch(void* const* d_in, const int* in_sizes, int n_in,
                              void* d_out, int out_size, void* d_ws, size_t ws_size,
                              hipStream_t stream) {
    const float* ctx = (const float*)d_in[0];
    const float* qst = (const float*)d_in[1];
    const float* w   = (const float*)d_in[2];
    float* out = (float*)d_out;
    float* ws  = (float*)d_ws;

    float* rowmax = ws + 32768;
    float* q2cvec = ws + 49152;

    hipMemsetAsync(q2cvec, 0, BB * DD * sizeof(float), stream);

    k_terms<<<(2 * BB * LC) / 4, 256, 0, stream>>>(ctx, qst, w, ws);

    k_main<<<dim3(LC / CTB, BB), 256, 0, stream>>>(ctx, qst, w, ws, out, rowmax);

    k_q2c<<<dim3(BB, 32), 256, 0, stream>>>(ctx, rowmax, q2cvec);

    k_bcast<<<(BB * LC * DD / 4) / 256, 256, 0, stream>>>(q2cvec, out + (size_t)BB * LC * DD);
}